// Round 3
// baseline (167.841 us; speedup 1.0000x reference)
//
#include <hip/hip_runtime.h>

#define DD 160
#define HH 192
#define WW 160
#define HWs (HH * WW)          // 30720
#define NTOT 9830400.0f        // 2*160*192*160
#define DOUT 10                // output slices per block
#define NIT  18                // DOUT + 8 halo
#define NBLK 1920              // 60 * 16 * 2

// ---- SD layout: [parity][row 0..23][g 0..9][ch-slot 0..5] in h4 (8 B) units.
// Row stride 62; rows get +2 per 8-row group; ch0..3 contiguous -> one b128
// write; ch4 at slot 4+(g&1). 62*8=496 and 6*8=48 are 16B multiples.
#define SDRS 62
#define SDP  1492              // parity stride, even
// ---- HS layout: [parity][ch 0..4][row 0..15][g 0..9] in h4 units.
#define HSRS 10
#define HSC  162
#define HSP  810

typedef float    v4 __attribute__((ext_vector_type(4)));
typedef _Float16 h4 __attribute__((ext_vector_type(4)));
typedef _Float16 h2 __attribute__((ext_vector_type(2)));
typedef _Float16 h8 __attribute__((ext_vector_type(8)));

// LDS-only barrier: leaves global prefetch loads in flight.
__device__ __forceinline__ void block_sync_lds() {
    __builtin_amdgcn_s_waitcnt(0xc07f);   // vmcnt=63, expcnt=7, lgkmcnt=0
    __builtin_amdgcn_s_barrier();
}
__device__ __forceinline__ v4 up(h4 x) { return __builtin_convertvector(x, v4); }
// packed RTZ downconvert: 2x v_cvt_pkrtz_f16_f32
__device__ __forceinline__ h4 dnp(v4 x) {
    h2 a = __builtin_bit_cast(h2, __builtin_amdgcn_cvt_pkrtz(x[0], x[1]));
    h2 b = __builtin_bit_cast(h2, __builtin_amdgcn_cvt_pkrtz(x[2], x[3]));
    return __builtin_shufflevector(a, b, 0, 1, 2, 3);
}

// Fully-fused NCC, D-first, ONE barrier per iteration (depth-3 phase pipeline):
//   ph1(t)   rt<240 : rolling 9-window D-sums {I,J,II,JJ,IJ}; 9-deep fp16
//                     reg FIFO; depth-1 prefetch; 2xb128+1xb64 -> SD[t&1]
//   ph2(t-1) rt<100 : 9-tap + 8-row slide H-sum over SD[(t-1)&1] -> HS
//   ph3(t-2) rt>=128: sliding W-sum over HS[t&1] + cc, 4 outputs/thread
// DOUT=10: grid 1920 blocks = 7.5 blocks/CU (was 3.75 -> occupancy-starved).
// LDS 37.9 KB -> 4 blocks/CU cap; VGPR budget sized for no spill (9-fifo,
// depth-1 prefetch, no ph2 register-keep -- r2's spill sources removed).
__global__ __launch_bounds__(256, 4) void kf(const float* __restrict__ I,
                                             const float* __restrict__ J,
                                             float* __restrict__ partial) {
    __shared__ __align__(16) h4 SDL[2 * SDP];   // 23872 B
    __shared__ __align__(16) h4 HSL[2 * HSP];   // 12960 B
    __shared__ float red[256];                  //  1024 B

    const int tid = threadIdx.x;
    const int bx = blockIdx.x, by = blockIdx.y, b = blockIdx.z;
    const int w0 = (bx % 5) * 32, h0 = (bx / 5) * 16;
    const int d0 = by * DOUT;
    const int bid = bx + 60 * (by + 16 * b);

    const int rt = tid ^ ((bx & 1) << 7);   // role swap waves 0,1 <-> 2,3

    // ---- ph1 decode: 240 columns = 24 rows x 10 f4-cols
    const bool p1 = rt < 240;
    const int r = rt / 10, g = rt % 10;
    const int gh = h0 - 4 + r, gw = w0 - 4 + g * 4;   // gw 16B-aligned
    const bool colOK = p1 && gh >= 0 && gh < HH && gw >= 0 && gw < WW;
    const size_t colOff = (size_t)gh * WW + gw;
    const float* Ib = I + (size_t)b * DD * HWs + colOff;
    const float* Jb = J + (size_t)b * DD * HWs + colOff;
    const int sdwOff = r * SDRS + (r >> 3) * 2 + 6 * g;

    // ---- ph2 decode: 100 tasks = 10 f4cols x 5 ch x 2 h-halves (8-row slide)
    const bool p2 = rt < 100;
    const int g2 = rt % 10, ch2 = (rt / 10) % 5, hh0 = (rt / 50) * 8;
    const int sdrOff = hh0 * SDRS + (hh0 >> 3) * 2 + 6 * g2 +
                       (ch2 == 4 ? 4 + (g2 & 1) : ch2);
    const int hswOff = ch2 * HSC + hh0 * HSRS + g2;

    // ---- ph3 decode: 128 tasks = 16 h-rows x 8 w-segments of 4 outputs
    const bool p3 = rt >= 128;
    const int q3 = rt & 127;
    const int hh = q3 >> 3, sg = q3 & 7;
    const int hsrOff = hh * HSRS + sg;

    v4 sd0 = 0.f, sd1 = 0.f, sd2 = 0.f, sd3 = 0.f, sd4 = 0.f;
    h4 fI[9], fJ[9];
#pragma unroll
    for (int uu = 0; uu < 9; ++uu) { fI[uu] = (h4)(_Float16)0; fJ[uu] = (h4)(_Float16)0; }
    v4 pLI = 0.f, pLJ = 0.f;
    float acc = 0.f;
    const float inv = 1.0f / 729.0f;

    {   // preload lead slice for t=0 (si = d0-4; <0 only for the d0=0 chunk)
        const int si = d0 - 4;
        if (colOK && si >= 0) {
            pLI = *(const v4*)(Ib + (size_t)si * HWs);
            pLJ = *(const v4*)(Jb + (size_t)si * HWs);
        }
    }

    // 20 = NIT+2 iterations; 9-unroll keeps fifo slot u = t%9 compile-time.
    for (int tb = 0; tb < 27; tb += 9) {
#pragma unroll
        for (int u = 0; u < 9; ++u) {
            const int t = tb + u;
            if (t < NIT + 2) {           // 20 iters; block-uniform guard
                // ---------- ph1(t): D-rolling, write SD[t&1]
                if (t < NIT && p1) {
                    h4 cI = dnp(pLI), cJ = dnp(pLJ);
                    v4 aI = up(cI), aJ = up(cJ);
                    v4 dI = aI, dJv = aJ;
                    v4 dII = aI * aI, dJJ = aJ * aJ, dIJ = aI * aJ;
                    if (t >= 9) {        // retire slice t-9 (fifo slot u)
                        v4 bI = up(fI[u]), bJ = up(fJ[u]);
                        dI -= bI; dJv -= bJ;
                        dII -= bI * bI; dJJ -= bJ * bJ; dIJ -= bI * bJ;
                    }
                    fI[u] = cI; fJ[u] = cJ;
                    sd0 += dI; sd1 += dJv; sd2 += dII; sd3 += dJJ; sd4 += dIJ;
                    h4* const qb = &SDL[(t & 1) * SDP + sdwOff];
                    h4 c0 = dnp(sd0), c1 = dnp(sd1), c2 = dnp(sd2), c3 = dnp(sd3);
                    *(h8*)qb       = __builtin_shufflevector(c0, c1, 0,1,2,3,4,5,6,7);
                    *(h8*)(qb + 2) = __builtin_shufflevector(c2, c3, 0,1,2,3,4,5,6,7);
                    qb[4 + (g & 1)] = dnp(sd4);
                    // prefetch next lead slice (stays in flight across barrier)
                    pLI = 0.f; pLJ = 0.f;
                    const int sn = d0 - 3 + t;
                    if (t + 1 < NIT && colOK && sn >= 0 && sn < DD) {
                        pLI = *(const v4*)(Ib + (size_t)sn * HWs);
                        pLJ = *(const v4*)(Jb + (size_t)sn * HWs);
                    }
                }

                // ---------- ph2(t-1): H-sums in packed fp16, write HS
                if (t >= 1 && t <= NIT && p2) {
                    const int par = (t - 1) & 1;
                    const h4* const sdr = &SDL[par * SDP + sdrOff];
                    h4* const hsw = &HSL[par * HSP + hswOff];
                    h4 s = sdr[0];
#pragma unroll
                    for (int k = 1; k < 9; ++k)
                        s += sdr[k * SDRS + (k >= 8 ? 2 : 0)];
                    hsw[0] = s;
#pragma unroll
                    for (int j = 1; j < 8; ++j) {
                        s += sdr[(j + 8) * SDRS + 2]
                           - sdr[(j - 1) * SDRS + (j - 1 >= 8 ? 2 : 0)];
                        hsw[j * HSRS] = s;
                    }
                }

                // ---------- ph3(t-2): W-slide + cc (output depth d0+t-10)
                if (t >= 10 && p3) {
                    const h4* const hsr = &HSL[(t & 1) * HSP + hsrOff];
                    float w[5][4];
#pragma unroll
                    for (int c = 0; c < 5; ++c) {
                        v4 fa = up(hsr[c * HSC]);
                        v4 fb = up(hsr[c * HSC + 1]);
                        v4 fc = up(hsr[c * HSC + 2]);
                        float s = fa[0] + fa[1] + fa[2] + fa[3] +
                                  fb[0] + fb[1] + fb[2] + fb[3] + fc[0];
                        w[c][0] = s;
                        s += fc[1] - fa[0]; w[c][1] = s;
                        s += fc[2] - fa[1]; w[c][2] = s;
                        s += fc[3] - fa[2]; w[c][3] = s;
                    }
#pragma unroll
                    for (int e = 0; e < 4; ++e) {
                        float mu1 = w[0][e] * inv, mu2 = w[1][e] * inv;
                        float g1  = fmaf(-mu1, mu1, w[2][e] * inv);
                        float g2v = fmaf(-mu2, mu2, w[3][e] * inv);
                        float g12 = fmaf(-mu1, mu2, w[4][e] * inv);
                        acc += __fdividef(g12 * g12, fmaf(g1, g2v, 1e-5f));
                    }
                }

                block_sync_lds();
            }
        }
    }

    red[tid] = acc;     // only p3 threads have nonzero acc
    __syncthreads();
    if (tid < 128) red[tid] += red[tid + 128];
    __syncthreads();
    if (tid < 64) {
        float a = red[tid] + red[tid + 64];
#pragma unroll
        for (int off = 32; off > 0; off >>= 1) a += __shfl_down(a, off);
        if (tid == 0) partial[bid] = a;
    }
}

__global__ void k3_final(const float* __restrict__ partial,
                         float* __restrict__ out) {
    __shared__ float r[1024];
    const int i = threadIdx.x;
    float v = (i < NBLK) ? partial[i] : 0.f;
    if (i + 1024 < NBLK) v += partial[i + 1024];
    r[i] = v;
    __syncthreads();
    for (int off = 512; off > 0; off >>= 1) {
        if (i < off) r[i] += r[i + off];
        __syncthreads();
    }
    if (i == 0) out[0] = -r[0] * (1.0f / NTOT);
}

extern "C" void kernel_launch(void* const* d_in, const int* in_sizes, int n_in,
                              void* d_out, int out_size, void* d_ws, size_t ws_size,
                              hipStream_t stream) {
    (void)in_sizes; (void)n_in; (void)out_size; (void)ws_size;
    const float* I = (const float*)d_in[0];   // y_true
    const float* J = (const float*)d_in[1];   // y_pred
    float* out     = (float*)d_out;
    float* partial = (float*)d_ws;            // NBLK floats, all written

    dim3 grid(60, 16, 2);                     // (5w x 12h tiles, D/10, B)
    kf<<<grid, 256, 0, stream>>>(I, J, partial);
    k3_final<<<1, 1024, 0, stream>>>(partial, out);
}

// Round 5
// 150.725 us; speedup vs baseline: 1.1136x; 1.1136x over previous
//
#include <hip/hip_runtime.h>

#define DD 160
#define HH 192
#define WW 160
#define HWs (HH * WW)          // 30720
#define NTOT 9830400.0f        // 2*160*192*160
#define DOUT 10                // output slices per block
#define NIT  18                // DOUT + 8 halo
#define NBLK 1920              // 60 * 16 * 2

// ---- SD layout (f16): [parity][row 0..23][g 0..9][ch-slot 0..5], h4 units.
// Row stride 62; +2 per 8-row group; ch0..3 contiguous -> b128 write;
// ch4 at slot 4+(g&1).
#define SDRS 62
#define SDP  1492
// ---- HS layout (f32): [parity][ch 0..4][row 0..15][g 0..9], v4 units.
#define HSRS 10
#define HSC  162
#define HSP  810

typedef float    v4 __attribute__((ext_vector_type(4)));
typedef _Float16 h4 __attribute__((ext_vector_type(4)));
typedef _Float16 h2 __attribute__((ext_vector_type(2)));
typedef _Float16 h8 __attribute__((ext_vector_type(8)));

// LDS-only barrier: leaves global prefetch loads in flight.
__device__ __forceinline__ void block_sync_lds() {
    __builtin_amdgcn_s_waitcnt(0xc07f);   // vmcnt=63, expcnt=7, lgkmcnt=0
    __builtin_amdgcn_s_barrier();
}
__device__ __forceinline__ v4 up(h4 x) { return __builtin_convertvector(x, v4); }
__device__ __forceinline__ h4 dnp(v4 x) {
    h2 a = __builtin_bit_cast(h2, __builtin_amdgcn_cvt_pkrtz(x[0], x[1]));
    h2 b = __builtin_bit_cast(h2, __builtin_amdgcn_cvt_pkrtz(x[2], x[3]));
    return __builtin_shufflevector(a, b, 0, 1, 2, 3);
}

// Fully-fused NCC, D-first, ONE barrier per iteration (depth-3 phase pipeline):
//   ph1(t)   rt<240 : rolling 9-window D-sums {I,J,II,JJ,IJ} in PURE f32 --
//                     retiring slice is RE-READ from global (L2/L3-resident,
//                     bit-identical => exact cancellation, no f16 round-trip,
//                     no register FIFO). Writes f16 SD[t&1].
//   ph2(t-1) rt<100 : 9-tap + 8-row slide H-sum over SD[(t-1)&1] in packed
//                     f16; writes f32 HS (one upconvert per write).
//   ph3(t-2) rt>=128: sliding W-sum over f32 HS[t&1] (b128 reads, zero
//                     converts) + cc, 4 outputs/thread.
// XCD-bijective block swizzle: 240 consecutive tile-ids per XCD so H/W-halo
// and old-slice re-reads hit the per-XCD L2.
// LDS 50.8 KB -> 3 blocks/CU.
__global__ __launch_bounds__(256, 3) void kf(const float* __restrict__ I,
                                             const float* __restrict__ J,
                                             float* __restrict__ partial) {
    __shared__ __align__(16) h4 SDL[2 * SDP];   // 23872 B
    __shared__ __align__(16) v4 HSL[2 * HSP];   // 25920 B
    __shared__ float red[256];                  //  1024 B

    const int tid = threadIdx.x;
    // XCD swizzle: wgid -> 8 chunks of 240 consecutive linear tile ids.
    const int wgid = blockIdx.x;
    const int tl = (wgid & 7) * 240 + (wgid >> 3);
    const int bx = tl % 60, by = (tl / 60) % 16, b = tl / 960;
    const int w0 = (bx % 5) * 32, h0 = (bx / 5) * 16;
    const int d0 = by * DOUT;
    const int bid = tl;

    const int rt = tid ^ ((bx & 1) << 7);   // role swap waves 0,1 <-> 2,3

    // ---- ph1 decode: 240 columns = 24 rows x 10 f4-cols
    const bool p1 = rt < 240;
    const int r = rt / 10, g = rt % 10;
    const int gh = h0 - 4 + r, gw = w0 - 4 + g * 4;   // gw 16B-aligned
    const bool colOK = p1 && gh >= 0 && gh < HH && gw >= 0 && gw < WW;
    const size_t colOff = (size_t)gh * WW + gw;
    const float* Ib = I + (size_t)b * DD * HWs + colOff;
    const float* Jb = J + (size_t)b * DD * HWs + colOff;
    const int sdwOff = r * SDRS + (r >> 3) * 2 + 6 * g;

    // ---- ph2 decode: 100 tasks = 10 f4cols x 5 ch x 2 h-halves (8-row slide)
    const bool p2 = rt < 100;
    const int g2 = rt % 10, ch2 = (rt / 10) % 5, hh0 = (rt / 50) * 8;
    const int sdrOff = hh0 * SDRS + (hh0 >> 3) * 2 + 6 * g2 +
                       (ch2 == 4 ? 4 + (g2 & 1) : ch2);
    const int hswOff = ch2 * HSC + hh0 * HSRS + g2;

    // ---- ph3 decode: 128 tasks = 16 h-rows x 8 w-segments of 4 outputs
    const bool p3 = rt >= 128;
    const int q3 = rt & 127;
    const int hh = q3 >> 3, sg = q3 & 7;
    const int hsrOff = hh * HSRS + sg;

    v4 sd0 = 0.f, sd1 = 0.f, sd2 = 0.f, sd3 = 0.f, sd4 = 0.f;
    v4 pLI = 0.f, pLJ = 0.f;   // lead-slice prefetch (slice d0-4+t)
    v4 pOI = 0.f, pOJ = 0.f;   // retiring-slice re-read prefetch (d0-13+t)
    float acc = 0.f;
    const float inv = 1.0f / 729.0f;

    {   // preload lead slice for t=0
        const int si = d0 - 4;
        if (colOK && si >= 0) {
            pLI = *(const v4*)(Ib + (size_t)si * HWs);
            pLJ = *(const v4*)(Jb + (size_t)si * HWs);
        }
    }

#pragma unroll
    for (int t = 0; t < NIT + 2; ++t) {
        // ---------- ph1(t): f32 D-rolling, write SD[t&1]
        if (t < NIT && p1) {
            const v4 cI = pLI, cJ = pLJ;
            v4 dI = cI, dJv = cJ;
            v4 dII = cI * cI, dJJ = cJ * cJ, dIJ = cI * cJ;
            if (t >= 9) {       // retire slice t-9 via bit-identical re-read
                dI  -= pOI;        dJv -= pOJ;
                dII -= pOI * pOI;  dJJ -= pOJ * pOJ;  dIJ -= pOI * pOJ;
            }
            sd0 += dI; sd1 += dJv; sd2 += dII; sd3 += dJJ; sd4 += dIJ;
            h4* const qb = &SDL[(t & 1) * SDP + sdwOff];
            h4 c0 = dnp(sd0), c1 = dnp(sd1), c2 = dnp(sd2), c3 = dnp(sd3);
            *(h8*)qb       = __builtin_shufflevector(c0, c1, 0,1,2,3,4,5,6,7);
            *(h8*)(qb + 2) = __builtin_shufflevector(c2, c3, 0,1,2,3,4,5,6,7);
            qb[4 + (g & 1)] = dnp(sd4);
            // prefetch lead slice for t+1 (in flight across barrier)
            pLI = 0.f; pLJ = 0.f;
            const int sn = d0 - 3 + t;
            if (t + 1 < NIT && colOK && sn >= 0 && sn < DD) {
                pLI = *(const v4*)(Ib + (size_t)sn * HWs);
                pLJ = *(const v4*)(Jb + (size_t)sn * HWs);
            }
            // prefetch retiring slice for t+1 (slice d0-12+t; L2/L3 hit)
            pOI = 0.f; pOJ = 0.f;
            const int so = d0 - 12 + t;
            if (t >= 8 && t + 1 < NIT && colOK && so >= 0) {
                pOI = *(const v4*)(Ib + (size_t)so * HWs);
                pOJ = *(const v4*)(Jb + (size_t)so * HWs);
            }
        }

        // ---------- ph2(t-1): packed-f16 H-sums over SD, write f32 HS
        if (t >= 1 && t <= NIT && p2) {
            const int par = (t - 1) & 1;
            const h4* const sdr = &SDL[par * SDP + sdrOff];
            v4* const hsw = &HSL[par * HSP + hswOff];
            h4 s = sdr[0];
#pragma unroll
            for (int k = 1; k < 9; ++k)
                s += sdr[k * SDRS + (k >= 8 ? 2 : 0)];
            hsw[0] = up(s);
#pragma unroll
            for (int j = 1; j < 8; ++j) {
                s += sdr[(j + 8) * SDRS + 2] - sdr[(j - 1) * SDRS];
                hsw[j * HSRS] = up(s);
            }
        }

        // ---------- ph3(t-2): f32 W-slide + cc (output depth d0+t-10)
        if (t >= 10 && p3) {
            const v4* const hsr = &HSL[(t & 1) * HSP + hsrOff];
            float w[5][4];
#pragma unroll
            for (int c = 0; c < 5; ++c) {
                v4 fa = hsr[c * HSC];
                v4 fb = hsr[c * HSC + 1];
                v4 fc = hsr[c * HSC + 2];
                float s = fa[0] + fa[1] + fa[2] + fa[3] +
                          fb[0] + fb[1] + fb[2] + fb[3] + fc[0];
                w[c][0] = s;
                s += fc[1] - fa[0]; w[c][1] = s;
                s += fc[2] - fa[1]; w[c][2] = s;
                s += fc[3] - fa[2]; w[c][3] = s;
            }
#pragma unroll
            for (int e = 0; e < 4; ++e) {
                float mu1 = w[0][e] * inv, mu2 = w[1][e] * inv;
                float g1  = fmaf(-mu1, mu1, w[2][e] * inv);
                float g2v = fmaf(-mu2, mu2, w[3][e] * inv);
                float g12 = fmaf(-mu1, mu2, w[4][e] * inv);
                acc += __fdividef(g12 * g12, fmaf(g1, g2v, 1e-5f));
            }
        }

        block_sync_lds();
    }

    red[tid] = acc;     // only p3 threads have nonzero acc
    __syncthreads();
    if (tid < 128) red[tid] += red[tid + 128];
    __syncthreads();
    if (tid < 64) {
        float a = red[tid] + red[tid + 64];
#pragma unroll
        for (int off = 32; off > 0; off >>= 1) a += __shfl_down(a, off);
        if (tid == 0) partial[bid] = a;
    }
}

__global__ void k3_final(const float* __restrict__ partial,
                         float* __restrict__ out) {
    __shared__ float r[1024];
    const int i = threadIdx.x;
    float v = (i < NBLK) ? partial[i] : 0.f;
    if (i + 1024 < NBLK) v += partial[i + 1024];
    r[i] = v;
    __syncthreads();
    for (int off = 512; off > 0; off >>= 1) {
        if (i < off) r[i] += r[i + off];
        __syncthreads();
    }
    if (i == 0) out[0] = -r[0] * (1.0f / NTOT);
}

extern "C" void kernel_launch(void* const* d_in, const int* in_sizes, int n_in,
                              void* d_out, int out_size, void* d_ws, size_t ws_size,
                              hipStream_t stream) {
    (void)in_sizes; (void)n_in; (void)out_size; (void)ws_size;
    const float* I = (const float*)d_in[0];   // y_true
    const float* J = (const float*)d_in[1];   // y_pred
    float* out     = (float*)d_out;
    float* partial = (float*)d_ws;            // NBLK floats, all written

    kf<<<dim3(NBLK), 256, 0, stream>>>(I, J, partial);
    k3_final<<<1, 1024, 0, stream>>>(partial, out);
}

// Round 6
// 141.485 us; speedup vs baseline: 1.1863x; 1.0653x over previous
//
#include <hip/hip_runtime.h>

#define DD 160
#define HH 192
#define WW 160
#define HWs (HH * WW)          // 30720
#define NTOT 9830400.0f        // 2*160*192*160
#define DOUT 20                // output slices per block
#define NIT  28                // DOUT + 8 halo
#define NBLK 960               // 60 * 8 * 2

// ---- SD layout (f16): [parity][row 0..23][g 0..9][ch-slot 0..5], h4 units.
// Row stride 62; +2 per 8-row group; ch0..3 contiguous -> b128 write;
// ch4 at slot 4+(g&1).
#define SDRS 62
#define SDP  1492
// ---- HS layout (f16): [parity][ch 0..4][row 0..15][g 0..9], h4 units.
#define HSRS 10
#define HSC  162
#define HSP  810

typedef float    v4 __attribute__((ext_vector_type(4)));
typedef _Float16 h4 __attribute__((ext_vector_type(4)));
typedef _Float16 h2 __attribute__((ext_vector_type(2)));
typedef _Float16 h8 __attribute__((ext_vector_type(8)));

// LDS-only barrier: leaves global prefetch loads in flight.
__device__ __forceinline__ void block_sync_lds() {
    __builtin_amdgcn_s_waitcnt(0xc07f);   // vmcnt=63, expcnt=7, lgkmcnt=0
    __builtin_amdgcn_s_barrier();
}
__device__ __forceinline__ v4 up(h4 x) { return __builtin_convertvector(x, v4); }
__device__ __forceinline__ h4 dnp(v4 x) {
    h2 a = __builtin_bit_cast(h2, __builtin_amdgcn_cvt_pkrtz(x[0], x[1]));
    h2 b = __builtin_bit_cast(h2, __builtin_amdgcn_cvt_pkrtz(x[2], x[3]));
    return __builtin_shufflevector(a, b, 0, 1, 2, 3);
}

// Fully-fused NCC, D-first, ONE barrier per iteration (depth-3 phase pipeline):
//   ph1(t)   rt<240 : rolling 9-window D-sums {I,J,II,JJ,IJ} in PURE f32 --
//                     retiring slice RE-READ from global (L2/L3-resident,
//                     bit-identical => exact cancellation, no reg FIFO).
//                     Writes f16 SD[t&1] as 2xb128+1xb64.
//   ph2(t-1) rt<100 : 9-tap + 8-row slide H-sum over SD[(t-1)&1], packed f16;
//                     initial rows 0..6 kept in regs (16 reads, not 23) -> HS
//   ph3(t-2) rt>=128: sliding W-sum over f16 HS[t&1] + cc, 4 outputs/thread
// DOUT=20: halo tax 1.4x (vs 1.8x at DOUT=10); LDS 37.9 KB -> 4 blocks/CU so
// all 960 blocks are co-resident (3.75/CU). f16 HS + ph2 reg-keep cut the
// LDS-pipe bytes/block-iter from 66 KB to ~39 KB (LDS pipe is the hot one:
// ~67% busy vs VALU 38% in r5). XCD-bijective swizzle: 120 tiles per XCD.
__global__ __launch_bounds__(256, 4) void kf(const float* __restrict__ I,
                                             const float* __restrict__ J,
                                             float* __restrict__ partial) {
    __shared__ __align__(16) h4 SDL[2 * SDP];   // 23872 B
    __shared__ __align__(16) h4 HSL[2 * HSP];   // 12960 B
    __shared__ float red[256];                  //  1024 B

    const int tid = threadIdx.x;
    // XCD swizzle: 8 chunks of 120 consecutive linear tile ids.
    const int wgid = blockIdx.x;
    const int tl = (wgid & 7) * 120 + (wgid >> 3);
    const int bx = tl % 60, by = (tl / 60) % 8, b = tl / 480;
    const int w0 = (bx % 5) * 32, h0 = (bx / 5) * 16;
    const int d0 = by * DOUT;
    const int bid = tl;

    const int rt = tid ^ ((bx & 1) << 7);   // role swap waves 0,1 <-> 2,3

    // ---- ph1 decode: 240 columns = 24 rows x 10 f4-cols
    const bool p1 = rt < 240;
    const int r = rt / 10, g = rt % 10;
    const int gh = h0 - 4 + r, gw = w0 - 4 + g * 4;   // gw 16B-aligned
    const bool colOK = p1 && gh >= 0 && gh < HH && gw >= 0 && gw < WW;
    const size_t colOff = (size_t)gh * WW + gw;
    const float* Ib = I + (size_t)b * DD * HWs + colOff;
    const float* Jb = J + (size_t)b * DD * HWs + colOff;
    const int sdwOff = r * SDRS + (r >> 3) * 2 + 6 * g;

    // ---- ph2 decode: 100 tasks = 10 f4cols x 5 ch x 2 h-halves (8-row slide)
    const bool p2 = rt < 100;
    const int g2 = rt % 10, ch2 = (rt / 10) % 5, hh0 = (rt / 50) * 8;
    const int sdrOff = hh0 * SDRS + (hh0 >> 3) * 2 + 6 * g2 +
                       (ch2 == 4 ? 4 + (g2 & 1) : ch2);
    const int hswOff = ch2 * HSC + hh0 * HSRS + g2;

    // ---- ph3 decode: 128 tasks = 16 h-rows x 8 w-segments of 4 outputs
    const bool p3 = rt >= 128;
    const int q3 = rt & 127;
    const int hh = q3 >> 3, sg = q3 & 7;
    const int hsrOff = hh * HSRS + sg;

    v4 sd0 = 0.f, sd1 = 0.f, sd2 = 0.f, sd3 = 0.f, sd4 = 0.f;
    v4 pLI = 0.f, pLJ = 0.f;   // lead-slice prefetch (slice d0-4+t)
    v4 pOI = 0.f, pOJ = 0.f;   // retiring-slice re-read prefetch
    float acc = 0.f;
    const float inv = 1.0f / 729.0f;

    {   // preload lead slice for t=0
        const int si = d0 - 4;
        if (colOK && si >= 0) {
            pLI = *(const v4*)(Ib + (size_t)si * HWs);
            pLJ = *(const v4*)(Jb + (size_t)si * HWs);
        }
    }

#pragma unroll
    for (int t = 0; t < NIT + 2; ++t) {
        // ---------- ph1(t): f32 D-rolling, write SD[t&1]
        if (t < NIT && p1) {
            const v4 cI = pLI, cJ = pLJ;
            v4 dI = cI, dJv = cJ;
            v4 dII = cI * cI, dJJ = cJ * cJ, dIJ = cI * cJ;
            if (t >= 9) {       // retire slice t-9 via bit-identical re-read
                dI  -= pOI;        dJv -= pOJ;
                dII -= pOI * pOI;  dJJ -= pOJ * pOJ;  dIJ -= pOI * pOJ;
            }
            sd0 += dI; sd1 += dJv; sd2 += dII; sd3 += dJJ; sd4 += dIJ;
            h4* const qb = &SDL[(t & 1) * SDP + sdwOff];
            h4 c0 = dnp(sd0), c1 = dnp(sd1), c2 = dnp(sd2), c3 = dnp(sd3);
            *(h8*)qb       = __builtin_shufflevector(c0, c1, 0,1,2,3,4,5,6,7);
            *(h8*)(qb + 2) = __builtin_shufflevector(c2, c3, 0,1,2,3,4,5,6,7);
            qb[4 + (g & 1)] = dnp(sd4);
            // prefetch lead slice for t+1 (in flight across barrier)
            pLI = 0.f; pLJ = 0.f;
            const int sn = d0 - 3 + t;
            if (t + 1 < NIT && colOK && sn >= 0 && sn < DD) {
                pLI = *(const v4*)(Ib + (size_t)sn * HWs);
                pLJ = *(const v4*)(Jb + (size_t)sn * HWs);
            }
            // prefetch retiring slice for t+1 (L2/L3 hit)
            pOI = 0.f; pOJ = 0.f;
            const int so = d0 - 12 + t;
            if (t >= 8 && t + 1 < NIT && colOK && so >= 0) {
                pOI = *(const v4*)(Ib + (size_t)so * HWs);
                pOJ = *(const v4*)(Jb + (size_t)so * HWs);
            }
        }

        // ---------- ph2(t-1): packed-f16 H-sums over SD, reg-keep, write HS
        if (t >= 1 && t <= NIT && p2) {
            const int par = (t - 1) & 1;
            const h4* const sdr = &SDL[par * SDP + sdrOff];
            h4* const hsw = &HSL[par * HSP + hswOff];
            h4 keep[7];                 // rows 0..6 of the initial window
            h4 s = sdr[0];
            keep[0] = s;
#pragma unroll
            for (int k = 1; k < 9; ++k) {
                h4 v = sdr[k * SDRS + (k >= 8 ? 2 : 0)];
                if (k < 7) keep[k] = v;
                s += v;
            }
            hsw[0] = s;
#pragma unroll
            for (int j = 1; j < 8; ++j) {
                s += sdr[(j + 8) * SDRS + 2] - keep[j - 1];
                hsw[j * HSRS] = s;
            }
        }

        // ---------- ph3(t-2): f16 W-slide + cc (output depth d0+t-10)
        if (t >= 10 && p3) {
            const h4* const hsr = &HSL[(t & 1) * HSP + hsrOff];
            float w[5][4];
#pragma unroll
            for (int c = 0; c < 5; ++c) {
                v4 fa = up(hsr[c * HSC]);
                v4 fb = up(hsr[c * HSC + 1]);
                v4 fc = up(hsr[c * HSC + 2]);
                float s = fa[0] + fa[1] + fa[2] + fa[3] +
                          fb[0] + fb[1] + fb[2] + fb[3] + fc[0];
                w[c][0] = s;
                s += fc[1] - fa[0]; w[c][1] = s;
                s += fc[2] - fa[1]; w[c][2] = s;
                s += fc[3] - fa[2]; w[c][3] = s;
            }
#pragma unroll
            for (int e = 0; e < 4; ++e) {
                float mu1 = w[0][e] * inv, mu2 = w[1][e] * inv;
                float g1  = fmaf(-mu1, mu1, w[2][e] * inv);
                float g2v = fmaf(-mu2, mu2, w[3][e] * inv);
                float g12 = fmaf(-mu1, mu2, w[4][e] * inv);
                acc += __fdividef(g12 * g12, fmaf(g1, g2v, 1e-5f));
            }
        }

        block_sync_lds();
    }

    red[tid] = acc;     // only p3 threads have nonzero acc
    __syncthreads();
    if (tid < 128) red[tid] += red[tid + 128];
    __syncthreads();
    if (tid < 64) {
        float a = red[tid] + red[tid + 64];
#pragma unroll
        for (int off = 32; off > 0; off >>= 1) a += __shfl_down(a, off);
        if (tid == 0) partial[bid] = a;
    }
}

__global__ void k3_final(const float* __restrict__ partial,
                         float* __restrict__ out) {
    __shared__ float r[1024];
    const int i = threadIdx.x;
    r[i] = (i < NBLK) ? partial[i] : 0.f;
    __syncthreads();
    for (int off = 512; off > 0; off >>= 1) {
        if (i < off) r[i] += r[i + off];
        __syncthreads();
    }
    if (i == 0) out[0] = -r[0] * (1.0f / NTOT);
}

extern "C" void kernel_launch(void* const* d_in, const int* in_sizes, int n_in,
                              void* d_out, int out_size, void* d_ws, size_t ws_size,
                              hipStream_t stream) {
    (void)in_sizes; (void)n_in; (void)out_size; (void)ws_size;
    const float* I = (const float*)d_in[0];   // y_true
    const float* J = (const float*)d_in[1];   // y_pred
    float* out     = (float*)d_out;
    float* partial = (float*)d_ws;            // NBLK floats, all written

    kf<<<dim3(NBLK), 256, 0, stream>>>(I, J, partial);
    k3_final<<<1, 1024, 0, stream>>>(partial, out);
}